// Round 8
// baseline (165.270 us; speedup 1.0000x reference)
//
#include <hip/hip_runtime.h>

// SWA non-overlapping window MHA, MI355X gfx950.
// K1 convert fp32->bf16 (x, w_in, w_out)
// K2 QKV GEMM [32768x1536x512]: 256x256xBK64, unit-staggered pipeline (vmcnt(4))
// K3 attention per (window, head) -> ctx bf16 [M][512]
// K4 out-proj GEMM [32768x512x512] + bias -> fp32 d_out (same loop, direct epilogue)

typedef __bf16 bf16x8 __attribute__((ext_vector_type(8)));
typedef float  f32x4  __attribute__((ext_vector_type(4)));

#define MFMA16(a, b, c) __builtin_amdgcn_mfma_f32_16x16x32_bf16((a), (b), (c), 0, 0, 0)
#define VMCNT_(n) asm volatile("s_waitcnt vmcnt(" #n ")" ::: "memory")
#define VMCNT(n) VMCNT_(n)
#define LGKM0() asm volatile("s_waitcnt lgkmcnt(0)" ::: "memory")

__device__ __forceinline__ void gload_lds16(const __bf16* g, void* l) {
    __builtin_amdgcn_global_load_lds(
        (const __attribute__((address_space(1))) unsigned int*)g,
        (__attribute__((address_space(3))) unsigned int*)l, 16, 0, 0);
}

// ---------------- K1: fp32 -> bf16 conversion ----------------
__device__ __forceinline__ void cvt8(const float* __restrict__ s,
                                     __bf16* __restrict__ d, long i) {
    const float4* s4 = reinterpret_cast<const float4*>(s);
    float4 a = s4[2 * i], b = s4[2 * i + 1];
    bf16x8 v;
    v[0] = (__bf16)a.x; v[1] = (__bf16)a.y; v[2] = (__bf16)a.z; v[3] = (__bf16)a.w;
    v[4] = (__bf16)b.x; v[5] = (__bf16)b.y; v[6] = (__bf16)b.z; v[7] = (__bf16)b.w;
    *reinterpret_cast<bf16x8*>(d + 8 * i) = v;
}

__global__ void convert_k(const float* __restrict__ x,
                          const float* __restrict__ w_in,
                          const float* __restrict__ w_out,
                          __bf16* __restrict__ x_bf,
                          __bf16* __restrict__ w_in_bf,
                          __bf16* __restrict__ w_out_bf)
{
    long i0 = (long)blockIdx.x * blockDim.x + threadIdx.x;
    long stride = (long)gridDim.x * blockDim.x;
    for (long i = i0; i < 16777216 / 8; i += stride) cvt8(x, x_bf, i);
    for (long i = i0; i < 786432 / 8;   i += stride) cvt8(w_in, w_in_bf, i);
    for (long i = i0; i < 262144 / 8;   i += stride) cvt8(w_out, w_out_bf, i);
}

// ---------------- K2/K4: 256x256xBK64, unit-staggered 4-phase pipeline ----------------
// LDS: A dbuf d at d*32768 (unit kk at +kk*16384, [256 rows][64 B]); B at +65536.
// Per phase: stage ONE 32-k unit (2 loads/thread), ds_read one frag set,
// lgkm0+barrier, 16 MFMA. vmcnt(4) at P2/P4 only (consume lag 3-4 phases).
// Proven: stage(unit U of t+1) at phase p; old U last read >=3 barrier-separated
// phases earlier with lgkm0 drained => WAR safe. vmcnt(4)+bar at P4(t) retires
// P1,P2(t) stages = kk0 units of t+1, read at P1(t+1). Same at P2 for kk1.
template<int EPI, int NN>
__global__ __launch_bounds__(512, 2)
void gemm256(const __bf16* __restrict__ A,
             const __bf16* __restrict__ Bw,
             const float* __restrict__ bias,
             void* __restrict__ Cq,
             __bf16* __restrict__ vT)
{
    __shared__ __align__(16) char smem[131072];

    const int nwg = gridDim.x;
    const int chunk = nwg >> 3;                       // nwg % 8 == 0
    const int bid = blockIdx.x;
    const int wg = (bid & 7) * chunk + (bid >> 3);    // XCD-contiguous chunks
    const int nidx = wg % NN;
    const int midx = wg / NN;
    const long mbase = (long)midx * 256;
    const int colbase = nidx * 256;

    const int tid = threadIdx.x;
    const int w = tid >> 6, lane = tid & 63;
    const int lrow = lane & 15, hi = lane >> 4;
    const int quad = lane >> 4, sl = lane & 15;
    const int wm = w >> 2, wn = w & 3;                // wave tile 128x64

    // staging: thread -> (row = tid>>2 in 128-row call, 16B slot = tid&3),
    // global k-chunk pre-swizzled so LDS[row][slot] = chunk slot^((row>>1)&3)
    const int srow = tid >> 2;
    const int kchunk = (tid & 3) ^ ((srow >> 1) & 3);
    const __bf16* PA = A  + (mbase + srow) * 512 + kchunk * 8;
    const __bf16* PB = Bw + ((long)colbase + srow) * 512 + kchunk * 8;
    const int sbase = w * 1024;
    // read-side swizzle (wave-constant per lane): slot = hi ^ ((lrow>>1)&3)
    const int rd16 = (hi ^ ((lrow >> 1) & 3)) << 4;

    f32x4 acc[8][4];
    #pragma unroll
    for (int rt = 0; rt < 8; ++rt)
        #pragma unroll
        for (int ct = 0; ct < 4; ++ct) acc[rt][ct] = (f32x4){0.f, 0.f, 0.f, 0.f};

#define STG(TT, ISB, KK) {                                                        \
        char* d_ = smem + (ISB) * 65536 + ((TT) & 1) * 32768 + (KK) * 16384 + sbase; \
        const __bf16* p_ = ((ISB) ? PB : PA) + (TT) * 64 + (KK) * 32;             \
        gload_lds16(p_, d_);                                                      \
        gload_lds16(p_ + 128 * 512, d_ + 8192); }

    bf16x8 af[4], bfr[4];
#define RDB(T, KK) {                                                              \
        const char* Bb_ = smem + 65536 + ((T) & 1) * 32768 + (KK) * 16384;        \
        _Pragma("unroll")                                                         \
        for (int ct = 0; ct < 4; ++ct)                                            \
            bfr[ct] = *reinterpret_cast<const bf16x8*>(                           \
                Bb_ + (64 * wn + 16 * ct + lrow) * 64 + rd16); }
#define RDA(T, KK, R0) {                                                          \
        const char* Ab_ = smem + ((T) & 1) * 32768 + (KK) * 16384;                \
        _Pragma("unroll")                                                         \
        for (int i = 0; i < 4; ++i)                                               \
            af[i] = *reinterpret_cast<const bf16x8*>(                             \
                Ab_ + (128 * wm + 16 * ((R0) + i) + lrow) * 64 + rd16); }
#define FMA(R0) {                                                                 \
        __builtin_amdgcn_s_setprio(1);                                            \
        _Pragma("unroll")                                                         \
        for (int i = 0; i < 4; ++i)                                               \
            _Pragma("unroll")                                                     \
            for (int ct = 0; ct < 4; ++ct)                                        \
                acc[(R0) + i][ct] = MFMA16(af[i], bfr[ct], acc[(R0) + i][ct]);    \
        __builtin_amdgcn_s_setprio(0); }

    // prologue: tile0's 4 units; vmcnt(4) -> kk0 units (loads 1-4) landed
    STG(0, 0, 0); STG(0, 1, 0); STG(0, 0, 1); STG(0, 1, 1);
    VMCNT(4);
    __builtin_amdgcn_s_barrier();

    #pragma unroll 1
    for (int t = 0; t < 8; ++t) {
        // P1: stage A-kk0(t+1); read B kk0 + A rt0-3 kk0
        if (t < 7) STG(t + 1, 0, 0);
        RDB(t, 0); RDA(t, 0, 0);
        LGKM0();
        __builtin_amdgcn_s_barrier();
        FMA(0);
        // P2: stage B-kk0(t+1); read A rt4-7 kk0; guard kk1(t)
        if (t < 7) STG(t + 1, 1, 0);
        RDA(t, 0, 4);
        if (t < 7) { VMCNT(4); } else { VMCNT(0); }
        LGKM0();
        __builtin_amdgcn_s_barrier();
        FMA(4);
        // P3: stage A-kk1(t+1); read B kk1 + A rt0-3 kk1
        if (t < 7) STG(t + 1, 0, 1);
        RDB(t, 1); RDA(t, 1, 0);
        LGKM0();
        __builtin_amdgcn_s_barrier();
        FMA(0);
        // P4: stage B-kk1(t+1); read A rt4-7 kk1; guard kk0(t+1)
        if (t < 7) STG(t + 1, 1, 1);
        RDA(t, 1, 4);
        if (t < 7) { VMCNT(4); } else { VMCNT(0); }
        LGKM0();
        __builtin_amdgcn_s_barrier();
        FMA(4);
    }
#undef STG
#undef RDB
#undef RDA
#undef FMA

    // ---- epilogue (all LDS reads drained pre-barrier; smem reusable) ----
    const int colg0 = colbase + 64 * wn + lrow;
    if (EPI == 0) {
        if (colbase < 1024) {
            // q/k: LDS [256 tok][256 col] bf16, slot ^= row&31 -> coalesced 16B stores
            const float scale = (colbase < 512) ? 0.125f : 1.0f;
            __bf16* qk = (__bf16*)Cq;
            #pragma unroll
            for (int ct = 0; ct < 4; ++ct) {
                float b = bias[colg0 + 16 * ct];
                int col2 = (64 * wn + 16 * ct + lrow) * 2;
                #pragma unroll
                for (int rt = 0; rt < 8; ++rt)
                    #pragma unroll
                    for (int r = 0; r < 4; ++r) {
                        int row = 128 * wm + 16 * rt + 4 * hi + r;
                        *reinterpret_cast<__bf16*>(
                            smem + row * 512 + (col2 ^ ((row & 31) << 4))) =
                            (__bf16)((acc[rt][ct][r] + b) * scale);
                    }
            }
            LGKM0();
            __builtin_amdgcn_s_barrier();
            #pragma unroll
            for (int i = 0; i < 8; ++i) {
                int row = 32 * w + 4 * i + quad;
                #pragma unroll
                for (int h2 = 0; h2 < 2; ++h2) {
                    int slot = (16 * h2 + sl) ^ (row & 31);
                    bf16x8 v = *reinterpret_cast<const bf16x8*>(smem + row * 512 + slot * 16);
                    *reinterpret_cast<bf16x8*>(
                        qk + (mbase + row) * 1024 + colbase + h2 * 128 + sl * 8) = v;
                }
            }
        } else {
            // v: LDS transposed [256 e][256 tok] bf16 -> vT[win][e][tok]
            #pragma unroll
            for (int ct = 0; ct < 4; ++ct) {
                float b = bias[colg0 + 16 * ct];
                int e = 64 * wn + 16 * ct + lrow;
                #pragma unroll
                for (int rt = 0; rt < 8; ++rt)
                    #pragma unroll
                    for (int r = 0; r < 4; ++r) {
                        int tok = 128 * wm + 16 * rt + 4 * hi + r;
                        *reinterpret_cast<__bf16*>(
                            smem + e * 512 + ((tok * 2) ^ ((e & 31) << 4))) =
                            (__bf16)(acc[rt][ct][r] + b);
                    }
            }
            LGKM0();
            __builtin_amdgcn_s_barrier();
            #pragma unroll
            for (int i = 0; i < 8; ++i) {
                int e = 32 * w + 4 * i + quad;
                #pragma unroll
                for (int h2 = 0; h2 < 2; ++h2) {
                    int slot = (16 * h2 + sl) ^ (e & 31);
                    bf16x8 v = *reinterpret_cast<const bf16x8*>(smem + e * 512 + slot * 16);
                    *reinterpret_cast<bf16x8*>(
                        vT + (long)(2 * midx + h2) * 65536 +
                        (colbase - 1024 + e) * 128 + sl * 8) = v;
                }
            }
        }
    } else {
        // direct fp32 epilogue: 16 lanes store 16 consecutive fp32 = full sectors
        float* outp = (float*)Cq;
        #pragma unroll
        for (int ct = 0; ct < 4; ++ct) {
            int colg = colbase + 64 * wn + 16 * ct + lrow;
            float b = bias[colg];
            #pragma unroll
            for (int rt = 0; rt < 8; ++rt) {
                long row = mbase + 128 * wm + 16 * rt + 4 * hi;
                #pragma unroll
                for (int r = 0; r < 4; ++r)
                    outp[(row + r) * 512 + colg] = acc[rt][ct][r] + b;
            }
        }
    }
}

// ---------------- K3: attention per (window, head), no barriers ----------------
__global__ __launch_bounds__(256)
void swa_attn(const __bf16* __restrict__ qk,   // [32768][1024] q 0-511 (scaled), k 512-1023
              const __bf16* __restrict__ vT,   // [256][8][64][128]
              __bf16* __restrict__ ctx)        // [32768][512]
{
    __shared__ __bf16 p_lds[4][32][136];

    const int bid = blockIdx.x;
    const int win = bid >> 3, h = bid & 7;
    const int tid = threadIdx.x;
    const int w = tid >> 6, lane = tid & 63;
    const int lrow = lane & 15, hi = lane >> 4;
    const long tokb = (long)win * 128;

    bf16x8 qa[2][2];
    #pragma unroll
    for (int rt = 0; rt < 2; ++rt)
        #pragma unroll
        for (int ks = 0; ks < 2; ++ks)
            qa[rt][ks] = *reinterpret_cast<const bf16x8*>(
                qk + (tokb + 32 * w + 16 * rt + lrow) * 1024 + h * 64 + ks * 32 + hi * 8);

    f32x4 s[2][8];
    #pragma unroll
    for (int rt = 0; rt < 2; ++rt)
        #pragma unroll
        for (int ct = 0; ct < 8; ++ct) s[rt][ct] = (f32x4){0.f, 0.f, 0.f, 0.f};
    #pragma unroll
    for (int ks = 0; ks < 2; ++ks) {
        #pragma unroll
        for (int ct = 0; ct < 8; ++ct) {
            bf16x8 kb = *reinterpret_cast<const bf16x8*>(
                qk + (tokb + 16 * ct + lrow) * 1024 + 512 + h * 64 + ks * 32 + hi * 8);
            s[0][ct] = MFMA16(qa[0][ks], kb, s[0][ct]);
            s[1][ct] = MFMA16(qa[1][ks], kb, s[1][ct]);
        }
    }

    float inv[2][4];
    #pragma unroll
    for (int rt = 0; rt < 2; ++rt) {
        #pragma unroll
        for (int r = 0; r < 4; ++r) {
            float m = s[rt][0][r];
            #pragma unroll
            for (int ct = 1; ct < 8; ++ct) m = fmaxf(m, s[rt][ct][r]);
            m = fmaxf(m, __shfl_xor(m, 1));
            m = fmaxf(m, __shfl_xor(m, 2));
            m = fmaxf(m, __shfl_xor(m, 4));
            m = fmaxf(m, __shfl_xor(m, 8));
            float sum = 0.f;
            #pragma unroll
            for (int ct = 0; ct < 8; ++ct) {
                float e = __expf(s[rt][ct][r] - m);
                sum += e;
                p_lds[w][16 * rt + 4 * hi + r][16 * ct + lrow] = (__bf16)e;
            }
            sum += __shfl_xor(sum, 1);
            sum += __shfl_xor(sum, 2);
            sum += __shfl_xor(sum, 4);
            sum += __shfl_xor(sum, 8);
            inv[rt][r] = 1.f / sum;
        }
    }

    f32x4 o[2][4];
    #pragma unroll
    for (int rt = 0; rt < 2; ++rt)
        #pragma unroll
        for (int ct = 0; ct < 4; ++ct) o[rt][ct] = (f32x4){0.f, 0.f, 0.f, 0.f};
    const __bf16* vb = vT + ((long)win * 8 + h) * 64 * 128;
    #pragma unroll
    for (int kt = 0; kt < 4; ++kt) {
        bf16x8 pa0 = *reinterpret_cast<const bf16x8*>(&p_lds[w][lrow][32 * kt + 8 * hi]);
        bf16x8 pa1 = *reinterpret_cast<const bf16x8*>(&p_lds[w][16 + lrow][32 * kt + 8 * hi]);
        #pragma unroll
        for (int ct = 0; ct < 4; ++ct) {
            bf16x8 vf = *reinterpret_cast<const bf16x8*>(
                vb + (16 * ct + lrow) * 128 + 32 * kt + 8 * hi);
            o[0][ct] = MFMA16(pa0, vf, o[0][ct]);
            o[1][ct] = MFMA16(pa1, vf, o[1][ct]);
        }
    }

    #pragma unroll
    for (int rt = 0; rt < 2; ++rt)
        #pragma unroll
        for (int ct = 0; ct < 4; ++ct)
            #pragma unroll
            for (int r = 0; r < 4; ++r) {
                long tok = tokb + 32 * w + 16 * rt + 4 * hi + r;
                ctx[tok * 512 + h * 64 + 16 * ct + lrow] =
                    (__bf16)(o[rt][ct][r] * inv[rt][r]);
            }
}

extern "C" void kernel_launch(void* const* d_in, const int* in_sizes, int n_in,
                              void* d_out, int out_size, void* d_ws, size_t ws_size,
                              hipStream_t stream)
{
    const float* x     = (const float*)d_in[0];
    const float* w_in  = (const float*)d_in[1];
    const float* b_in  = (const float*)d_in[2];
    const float* w_out = (const float*)d_in[3];
    const float* b_out = (const float*)d_in[4];

    // ws: [x_bf -> later ctx: 0, 33554432) [vT: 33554432, 67108864)
    //     [w_in_bf: 67108864, +1572864) [w_out_bf: 68681728, +524288)
    // qk scratch (67.1 MB bf16) lives in d_out until K4 overwrites it.
    char* ws = (char*)d_ws;
    __bf16* x_bf     = (__bf16*)(ws);
    __bf16* ctx      = (__bf16*)(ws);                  // reuses x_bf after K2
    __bf16* vT       = (__bf16*)(ws + 33554432);
    __bf16* w_in_bf  = (__bf16*)(ws + 67108864);
    __bf16* w_out_bf = (__bf16*)(ws + 68681728);
    __bf16* qk       = (__bf16*)d_out;

    convert_k<<<2048, 256, 0, stream>>>(x, w_in, w_out, x_bf, w_in_bf, w_out_bf);
    gemm256<0, 6><<<768, 512, 0, stream>>>(x_bf, w_in_bf, b_in, (void*)qk, vT);
    swa_attn<<<2048, 256, 0, stream>>>(qk, vT, ctx);
    gemm256<1, 2><<<256, 512, 0, stream>>>(ctx, w_out_bf, b_out, d_out, nullptr);
}

// Round 9
// 163.048 us; speedup vs baseline: 1.0136x; 1.0136x over previous
//
#include <hip/hip_runtime.h>

// SWA non-overlapping window MHA, MI355X gfx950.
// K1 convert fp32->bf16 (x, w_in, w_out)
// K2 QKV GEMM [32768x1536x512]: 128x128xBK32, ring-3, 3 blocks/CU -> qk + vT
// K3 attention per (window, head) -> ctx bf16 [M][512]
// K4 out-proj GEMM [32768x512x512] + bias -> fp32 d_out (same template)

typedef __bf16 bf16x8 __attribute__((ext_vector_type(8)));
typedef float  f32x4  __attribute__((ext_vector_type(4)));

#define MFMA16(a, b, c) __builtin_amdgcn_mfma_f32_16x16x32_bf16((a), (b), (c), 0, 0, 0)
#define VMCNT_(n) asm volatile("s_waitcnt vmcnt(" #n ")" ::: "memory")
#define VMCNT(n) VMCNT_(n)
#define LGKM0() asm volatile("s_waitcnt lgkmcnt(0)" ::: "memory")

__device__ __forceinline__ void gload_lds16(const __bf16* g, void* l) {
    __builtin_amdgcn_global_load_lds(
        (const __attribute__((address_space(1))) unsigned int*)g,
        (__attribute__((address_space(3))) unsigned int*)l, 16, 0, 0);
}

// ---------------- K1: fp32 -> bf16 conversion ----------------
__device__ __forceinline__ void cvt8(const float* __restrict__ s,
                                     __bf16* __restrict__ d, long i) {
    const float4* s4 = reinterpret_cast<const float4*>(s);
    float4 a = s4[2 * i], b = s4[2 * i + 1];
    bf16x8 v;
    v[0] = (__bf16)a.x; v[1] = (__bf16)a.y; v[2] = (__bf16)a.z; v[3] = (__bf16)a.w;
    v[4] = (__bf16)b.x; v[5] = (__bf16)b.y; v[6] = (__bf16)b.z; v[7] = (__bf16)b.w;
    *reinterpret_cast<bf16x8*>(d + 8 * i) = v;
}

__global__ void convert_k(const float* __restrict__ x,
                          const float* __restrict__ w_in,
                          const float* __restrict__ w_out,
                          __bf16* __restrict__ x_bf,
                          __bf16* __restrict__ w_in_bf,
                          __bf16* __restrict__ w_out_bf)
{
    long i0 = (long)blockIdx.x * blockDim.x + threadIdx.x;
    long stride = (long)gridDim.x * blockDim.x;
    for (long i = i0; i < 16777216 / 8; i += stride) cvt8(x, x_bf, i);
    for (long i = i0; i < 786432 / 8;   i += stride) cvt8(w_in, w_in_bf, i);
    for (long i = i0; i < 262144 / 8;   i += stride) cvt8(w_out, w_out_bf, i);
}

// ---------------- K2/K4: 128x128xBK32 GEMM, ring-3, 3 blocks/CU ----------------
// LDS 48 KiB: slot s at s*16384 {A [128 rows][64 B], B at +8192}. 16 K-tiles.
// Iter t: VMCNT(4) [tile t landed, stage(t+1) in flight], LGKM0, barrier,
// stage(t+2) [4 loads], 8 ds_read_b128, 16 MFMA. 64 B pitch -> 2-way (free),
// no swizzle. Inter-block overlap (3/CU) hides prologue/epilogue/barrier waits.
template<int EPI, int NN>
__global__ __launch_bounds__(256, 3)
void gemm128(const __bf16* __restrict__ A,
             const __bf16* __restrict__ Bw,
             const float* __restrict__ bias,
             void* __restrict__ Cq,
             __bf16* __restrict__ vT)
{
    __shared__ __align__(16) char smem[49152];

    const int nwg = gridDim.x;
    const int chunk = nwg >> 3;                       // nwg % 8 == 0
    const int bid = blockIdx.x;
    const int wg = (bid & 7) * chunk + (bid >> 3);    // XCD-contiguous chunks
    const int nidx = wg % NN;
    const int midx = wg / NN;
    const long mbase = (long)midx * 128;
    const int colbase = nidx * 128;

    const int tid = threadIdx.x;
    const int w = tid >> 6, lane = tid & 63;
    const int lrow = lane & 15, hi = lane >> 4;
    const int wm = w >> 1, wn = w & 1;                // wave tile 64x64

    // staging: per gload, lanes cover 16 rows x 4 x 16B (= rows r0+(lane>>2), k-slot lane&3)
    const int srow = lane >> 2, sk = lane & 3;
    const __bf16* PA = A  + (mbase + 32 * w + srow) * 512 + sk * 8;
    const __bf16* PB = Bw + ((long)colbase + 32 * w + srow) * 512 + sk * 8;

    f32x4 acc[4][4];
    #pragma unroll
    for (int rt = 0; rt < 4; ++rt)
        #pragma unroll
        for (int ct = 0; ct < 4; ++ct) acc[rt][ct] = (f32x4){0.f, 0.f, 0.f, 0.f};

    auto stage = [&](int t, int slot) {               // 4 gload16/thread
        char* As = smem + slot * 16384;
        char* Bs = As + 8192;
        const int ko = t * 32;
        #pragma unroll
        for (int j = 0; j < 2; ++j) {
            gload_lds16(PA + ko + j * 16 * 512, As + (32 * w + 16 * j) * 64);
            gload_lds16(PB + ko + j * 16 * 512, Bs + (32 * w + 16 * j) * 64);
        }
    };

    // prologue: tiles 0,1 into slots 0,1 (8 loads/thread)
    stage(0, 0); stage(1, 1);

    #pragma unroll 1
    for (int t = 0; t < 16; ++t) {
        if (t < 15) { VMCNT(4); } else { VMCNT(0); }
        LGKM0();
        __builtin_amdgcn_s_barrier();
        if (t < 14) {
            int t2 = t + 2;
            stage(t2, t2 - (t2 >= 15 ? 15 : (t2 >= 12 ? 12 : (t2 >= 9 ? 9 : (t2 >= 6 ? 6 : (t2 >= 3 ? 3 : 0))))));
        }
        const int slot = t - (t >= 15 ? 15 : (t >= 12 ? 12 : (t >= 9 ? 9 : (t >= 6 ? 6 : (t >= 3 ? 3 : 0)))));
        const char* As = smem + slot * 16384;
        const char* Bs = As + 8192;
        bf16x8 af[4], bfr[4];
        #pragma unroll
        for (int i = 0; i < 4; ++i)
            af[i] = *reinterpret_cast<const bf16x8*>(
                As + (64 * wm + 16 * i + lrow) * 64 + hi * 16);
        #pragma unroll
        for (int ct = 0; ct < 4; ++ct)
            bfr[ct] = *reinterpret_cast<const bf16x8*>(
                Bs + (64 * wn + 16 * ct + lrow) * 64 + hi * 16);
        __builtin_amdgcn_s_setprio(1);
        #pragma unroll
        for (int i = 0; i < 4; ++i)
            #pragma unroll
            for (int ct = 0; ct < 4; ++ct)
                acc[i][ct] = MFMA16(af[i], bfr[ct], acc[i][ct]);
        __builtin_amdgcn_s_setprio(0);
    }
    LGKM0();
    __builtin_amdgcn_s_barrier();                     // ring reads done; smem reusable

    // ---- epilogue ----
    if (EPI == 0) {
        if (colbase < 1024) {
            // q/k: LDS [128 rows][pitch 288B], then coalesced 16B row stores
            const float scale = (colbase < 512) ? 0.125f : 1.0f;
            __bf16* qk = (__bf16*)Cq;
            #pragma unroll
            for (int ct = 0; ct < 4; ++ct) {
                int col = 64 * wn + 16 * ct + lrow;
                float b = bias[colbase + col];
                #pragma unroll
                for (int rt = 0; rt < 4; ++rt)
                    #pragma unroll
                    for (int r = 0; r < 4; ++r) {
                        int row = 64 * wm + 16 * rt + 4 * hi + r;
                        *reinterpret_cast<__bf16*>(smem + row * 288 + col * 2) =
                            (__bf16)((acc[rt][ct][r] + b) * scale);
                    }
            }
            LGKM0();
            __builtin_amdgcn_s_barrier();
            #pragma unroll
            for (int i = 0; i < 8; ++i) {
                int row = 16 * i + (tid >> 4);
                bf16x8 v = *reinterpret_cast<const bf16x8*>(smem + row * 288 + (tid & 15) * 16);
                *reinterpret_cast<bf16x8*>(
                    qk + (mbase + row) * 1024 + colbase + (tid & 15) * 8) = v;
            }
        } else {
            // v: transpose in LDS [128 e][pitch 288B over 128 toks] -> vT[win][e][tok]
            #pragma unroll
            for (int ct = 0; ct < 4; ++ct) {
                int e = 64 * wn + 16 * ct + lrow;
                float b = bias[colbase + e];
                #pragma unroll
                for (int rt = 0; rt < 4; ++rt)
                    #pragma unroll
                    for (int r = 0; r < 4; ++r) {
                        int tok = 64 * wm + 16 * rt + 4 * hi + r;
                        *reinterpret_cast<__bf16*>(smem + e * 288 + tok * 2) =
                            (__bf16)(acc[rt][ct][r] + b);
                    }
            }
            LGKM0();
            __builtin_amdgcn_s_barrier();
            #pragma unroll
            for (int i = 0; i < 8; ++i) {
                int e = 16 * i + (tid >> 4);
                bf16x8 v = *reinterpret_cast<const bf16x8*>(smem + e * 288 + (tid & 15) * 16);
                *reinterpret_cast<bf16x8*>(
                    vT + (long)midx * 65536 + (colbase - 1024 + e) * 128 + (tid & 15) * 8) = v;
            }
        }
    } else {
        // fp32 direct: 16 lanes x 4B = full 64B sectors
        float* outp = (float*)Cq;
        #pragma unroll
        for (int ct = 0; ct < 4; ++ct) {
            int colg = colbase + 64 * wn + 16 * ct + lrow;
            float b = bias[colg];
            #pragma unroll
            for (int rt = 0; rt < 4; ++rt) {
                long row = mbase + 64 * wm + 16 * rt + 4 * hi;
                #pragma unroll
                for (int r = 0; r < 4; ++r)
                    outp[(row + r) * 512 + colg] = acc[rt][ct][r] + b;
            }
        }
    }
}

// ---------------- K3: attention per (window, head), no barriers ----------------
__global__ __launch_bounds__(256)
void swa_attn(const __bf16* __restrict__ qk,   // [32768][1024] q 0-511 (scaled), k 512-1023
              const __bf16* __restrict__ vT,   // [256][8][64][128]
              __bf16* __restrict__ ctx)        // [32768][512]
{
    __shared__ __bf16 p_lds[4][32][136];

    const int bid = blockIdx.x;
    const int win = bid >> 3, h = bid & 7;
    const int tid = threadIdx.x;
    const int w = tid >> 6, lane = tid & 63;
    const int lrow = lane & 15, hi = lane >> 4;
    const long tokb = (long)win * 128;

    bf16x8 qa[2][2];
    #pragma unroll
    for (int rt = 0; rt < 2; ++rt)
        #pragma unroll
        for (int ks = 0; ks < 2; ++ks)
            qa[rt][ks] = *reinterpret_cast<const bf16x8*>(
                qk + (tokb + 32 * w + 16 * rt + lrow) * 1024 + h * 64 + ks * 32 + hi * 8);

    f32x4 s[2][8];
    #pragma unroll
    for (int rt = 0; rt < 2; ++rt)
        #pragma unroll
        for (int ct = 0; ct < 8; ++ct) s[rt][ct] = (f32x4){0.f, 0.f, 0.f, 0.f};
    #pragma unroll
    for (int ks = 0; ks < 2; ++ks) {
        #pragma unroll
        for (int ct = 0; ct < 8; ++ct) {
            bf16x8 kb = *reinterpret_cast<const bf16x8*>(
                qk + (tokb + 16 * ct + lrow) * 1024 + 512 + h * 64 + ks * 32 + hi * 8);
            s[0][ct] = MFMA16(qa[0][ks], kb, s[0][ct]);
            s[1][ct] = MFMA16(qa[1][ks], kb, s[1][ct]);
        }
    }

    float inv[2][4];
    #pragma unroll
    for (int rt = 0; rt < 2; ++rt) {
        #pragma unroll
        for (int r = 0; r < 4; ++r) {
            float m = s[rt][0][r];
            #pragma unroll
            for (int ct = 1; ct < 8; ++ct) m = fmaxf(m, s[rt][ct][r]);
            m = fmaxf(m, __shfl_xor(m, 1));
            m = fmaxf(m, __shfl_xor(m, 2));
            m = fmaxf(m, __shfl_xor(m, 4));
            m = fmaxf(m, __shfl_xor(m, 8));
            float sum = 0.f;
            #pragma unroll
            for (int ct = 0; ct < 8; ++ct) {
                float e = __expf(s[rt][ct][r] - m);
                sum += e;
                p_lds[w][16 * rt + 4 * hi + r][16 * ct + lrow] = (__bf16)e;
            }
            sum += __shfl_xor(sum, 1);
            sum += __shfl_xor(sum, 2);
            sum += __shfl_xor(sum, 4);
            sum += __shfl_xor(sum, 8);
            inv[rt][r] = 1.f / sum;
        }
    }

    f32x4 o[2][4];
    #pragma unroll
    for (int rt = 0; rt < 2; ++rt)
        #pragma unroll
        for (int ct = 0; ct < 4; ++ct) o[rt][ct] = (f32x4){0.f, 0.f, 0.f, 0.f};
    const __bf16* vb = vT + ((long)win * 8 + h) * 64 * 128;
    #pragma unroll
    for (int kt = 0; kt < 4; ++kt) {
        bf16x8 pa0 = *reinterpret_cast<const bf16x8*>(&p_lds[w][lrow][32 * kt + 8 * hi]);
        bf16x8 pa1 = *reinterpret_cast<const bf16x8*>(&p_lds[w][16 + lrow][32 * kt + 8 * hi]);
        #pragma unroll
        for (int ct = 0; ct < 4; ++ct) {
            bf16x8 vf = *reinterpret_cast<const bf16x8*>(
                vb + (16 * ct + lrow) * 128 + 32 * kt + 8 * hi);
            o[0][ct] = MFMA16(pa0, vf, o[0][ct]);
            o[1][ct] = MFMA16(pa1, vf, o[1][ct]);
        }
    }

    #pragma unroll
    for (int rt = 0; rt < 2; ++rt)
        #pragma unroll
        for (int ct = 0; ct < 4; ++ct)
            #pragma unroll
            for (int r = 0; r < 4; ++r) {
                long tok = tokb + 32 * w + 16 * rt + 4 * hi + r;
                ctx[tok * 512 + h * 64 + 16 * ct + lrow] =
                    (__bf16)(o[rt][ct][r] * inv[rt][r]);
            }
}

extern "C" void kernel_launch(void* const* d_in, const int* in_sizes, int n_in,
                              void* d_out, int out_size, void* d_ws, size_t ws_size,
                              hipStream_t stream)
{
    const float* x     = (const float*)d_in[0];
    const float* w_in  = (const float*)d_in[1];
    const float* b_in  = (const float*)d_in[2];
    const float* w_out = (const float*)d_in[3];
    const float* b_out = (const float*)d_in[4];

    // ws: [x_bf -> later ctx: 0, 33554432) [vT: 33554432, 67108864)
    //     [w_in_bf: 67108864, +1572864) [w_out_bf: 68681728, +524288)
    // qk scratch (67.1 MB bf16) lives in d_out until K4 overwrites it.
    char* ws = (char*)d_ws;
    __bf16* x_bf     = (__bf16*)(ws);
    __bf16* ctx      = (__bf16*)(ws);                  // reuses x_bf after K2
    __bf16* vT       = (__bf16*)(ws + 33554432);
    __bf16* w_in_bf  = (__bf16*)(ws + 67108864);
    __bf16* w_out_bf = (__bf16*)(ws + 68681728);
    __bf16* qk       = (__bf16*)d_out;

    convert_k<<<2048, 256, 0, stream>>>(x, w_in, w_out, x_bf, w_in_bf, w_out_bf);
    gemm128<0, 12><<<3072, 256, 0, stream>>>(x_bf, w_in_bf, b_in, (void*)qk, vT);
    swa_attn<<<2048, 256, 0, stream>>>(qk, vT, ctx);
    gemm128<1, 4><<<1024, 256, 0, stream>>>(ctx, w_out_bf, b_out, d_out, nullptr);
}